// Round 4
// baseline (145.437 us; speedup 1.0000x reference)
//
#include <hip/hip_runtime.h>
#include <math.h>

// Problem constants (reference: BATCH=4096, DIM=512, sigma = s*I).
#define NB 4096
#define ND 512
#define BT 64                       // block super-tile: 64x64 (4 waves x 32x32)
#define NT (NB / BT)                // 64 tile-rows
#define NBLK (NT * (NT + 1) / 2)    // 2080 lower-triangular blocks

typedef __bf16 bf16x8 __attribute__((ext_vector_type(8)));
typedef float floatx4 __attribute__((ext_vector_type(4)));

// Kernel 1: cast mu -> bf16 (one wave per row), hq[i] = 0.5*sum(bf16(x)^2),
// zero sumexp (ws is re-poisoned to 0xAA before every timed launch).
__global__ __launch_bounds__(256) void prep_kernel(const float* __restrict__ mu,
                                                   __bf16* __restrict__ mubf,
                                                   float* __restrict__ hq,
                                                   float* __restrict__ sumexp) {
    const int t = threadIdx.x;
    const int wave = t >> 6, lane = t & 63;
    const int row = blockIdx.x * 4 + wave;
    const float4* src = (const float4*)(mu + (size_t)row * ND) + lane * 2;
    const float4 v0 = src[0], v1 = src[1];
    bf16x8 pack;
    pack[0] = (__bf16)v0.x; pack[1] = (__bf16)v0.y;
    pack[2] = (__bf16)v0.z; pack[3] = (__bf16)v0.w;
    pack[4] = (__bf16)v1.x; pack[5] = (__bf16)v1.y;
    pack[6] = (__bf16)v1.z; pack[7] = (__bf16)v1.w;
    ((bf16x8*)(mubf + (size_t)row * ND))[lane] = pack;
    float sq = 0.0f;
    #pragma unroll
    for (int e = 0; e < 8; e++) { float f = (float)pack[e]; sq += f * f; }
    #pragma unroll
    for (int off = 32; off > 0; off >>= 1) sq += __shfl_down(sq, off, 64);
    if (lane == 0) {
        hq[row] = 0.5f * sq;
        sumexp[row] = 0.0f;
    }
}

// Kernel 2: barrier-free symmetric Gram + exp + row/col sum scatter.
// One BLOCK owns a 64x64 lower-triangular super-tile; each of its 4 waves
// computes one 32x32 quadrant (2x2 MFMA accs) with fragments loaded
// directly from global (bf16x8 = one 16B dwordx4 per lane). No LDS, no
// __syncthreads; 2080 blocks -> ~8 blocks/CU for latency tolerance.
// expo[i,j] = (G_ij - hq_i - hq_j)/s <= ~0 (max on diag = 0), so plain
// sum-of-exp is safe without an online max. Off-diag super-tiles also
// scatter their column sums to the mirrored rows (symmetry).
__global__ __launch_bounds__(256, 6) void gram_lse_kernel(const __bf16* __restrict__ mubf,
                                                          const float* __restrict__ hq,
                                                          const float* __restrict__ sigma,
                                                          float* __restrict__ sumexp) {
    const int t = threadIdx.x;
    const int wave = t >> 6;
    const int lane = t & 63;
    const int r16 = lane & 15;
    const int quad = lane >> 4;

    // Decode linear block id -> lower-triangular (ti >= tj) over 64-grid.
    const int b = blockIdx.x;
    int ti = (int)((sqrtf(8.0f * (float)b + 1.0f) - 1.0f) * 0.5f);
    while ((ti + 1) * (ti + 2) / 2 <= b) ti++;
    while (ti * (ti + 1) / 2 > b) ti--;
    const int tj = b - ti * (ti + 1) / 2;
    const bool isDiag = (ti == tj);
    const int qi = wave >> 1, qj = wave & 1;       // quadrant of the 64x64
    const int row0 = ti * BT + qi * 32;
    const int col0 = tj * BT + qj * 32;

    // Fragment base pointers: lane holds 8 contiguous k-elems of one row.
    const __bf16* pa[2];
    const __bf16* pb[2];
    #pragma unroll
    for (int i = 0; i < 2; i++)
        pa[i] = mubf + (size_t)(row0 + i * 16 + r16) * ND + quad * 8;
    #pragma unroll
    for (int j = 0; j < 2; j++)
        pb[j] = mubf + (size_t)(col0 + j * 16 + r16) * ND + quad * 8;

    floatx4 acc[2][2];
    #pragma unroll
    for (int i = 0; i < 2; i++)
        #pragma unroll
        for (int j = 0; j < 2; j++) {
            floatx4 z = {0.f, 0.f, 0.f, 0.f};
            acc[i][j] = z;
        }

    // 1-deep software pipeline over 16 k-steps (k += 32 per step).
    bf16x8 fa[2][2], fb[2][2];
    #pragma unroll
    for (int i = 0; i < 2; i++) fa[0][i] = *(const bf16x8*)pa[i];
    #pragma unroll
    for (int j = 0; j < 2; j++) fb[0][j] = *(const bf16x8*)pb[j];

    #pragma unroll
    for (int kk = 0; kk < 16; kk++) {
        const int cur = kk & 1, nxt = cur ^ 1;
        if (kk < 15) {
            #pragma unroll
            for (int i = 0; i < 2; i++) fa[nxt][i] = *(const bf16x8*)(pa[i] + (kk + 1) * 32);
            #pragma unroll
            for (int j = 0; j < 2; j++) fb[nxt][j] = *(const bf16x8*)(pb[j] + (kk + 1) * 32);
        }
        #pragma unroll
        for (int i = 0; i < 2; i++)
            #pragma unroll
            for (int j = 0; j < 2; j++)
                acc[i][j] = __builtin_amdgcn_mfma_f32_16x16x32_bf16(fa[cur][i], fb[cur][j], acc[i][j], 0, 0, 0);
    }

    // Epilogue. C/D layout (m89-verified): col = lane&15, row = quad*4 + reg.
    const float inv_s = 1.0f / sigma[0];
    float hqc[2];
    #pragma unroll
    for (int j = 0; j < 2; j++) hqc[j] = hq[col0 + j * 16 + r16];

    float cs[2] = {0.f, 0.f};                 // per-lane column partials
    #pragma unroll
    for (int i = 0; i < 2; i++) {
        #pragma unroll
        for (int r = 0; r < 4; r++) {
            const int row = row0 + i * 16 + quad * 4 + r;
            const float hr = hq[row];
            float rs = 0.0f;
            #pragma unroll
            for (int j = 0; j < 2; j++) {
                const float v = __expf((acc[i][j][r] - hr - hqc[j]) * inv_s);
                rs += v;
                cs[j] += v;
            }
            rs += __shfl_xor(rs, 1, 64);
            rs += __shfl_xor(rs, 2, 64);
            rs += __shfl_xor(rs, 4, 64);
            rs += __shfl_xor(rs, 8, 64);
            if (r16 == 0) atomicAdd(&sumexp[row], rs);
        }
    }
    if (!isDiag) {
        // Column sums -> mirrored rows (symmetry). Reduce across quads.
        // (Diag super-tiles compute both mirror quadrants, so rows suffice.)
        #pragma unroll
        for (int j = 0; j < 2; j++) {
            float c = cs[j];
            c += __shfl_xor(c, 16, 64);
            c += __shfl_xor(c, 32, 64);
            if (quad == 0) atomicAdd(&sumexp[col0 + j * 16 + r16], c);
        }
    }
}

// Kernel 3: entropy = D/2 + ln(B) + (D/2)ln(2*pi*s) - mean_i log(sumexp_i)
__global__ __launch_bounds__(1024) void finalize_kernel(const float* __restrict__ sumexp,
                                                        const float* __restrict__ sigma,
                                                        float* __restrict__ out) {
    const int t = threadIdx.x;
    float local = 0.0f;
    for (int i = t; i < NB; i += 1024) local += logf(sumexp[i]);
    #pragma unroll
    for (int off = 32; off > 0; off >>= 1) local += __shfl_down(local, off, 64);
    __shared__ float red[16];
    if ((t & 63) == 0) red[t >> 6] = local;
    __syncthreads();
    if (t == 0) {
        double tot = 0.0;
        #pragma unroll
        for (int i = 0; i < 16; i++) tot += (double)red[i];
        const double s = (double)sigma[0];
        const double ent = (double)(ND / 2)
                         + log((double)NB)
                         + (double)(ND / 2) * log(2.0 * M_PI * s)
                         - tot / (double)NB;
        out[0] = (float)ent;
        out[1] = (float)ent;
    }
}

extern "C" void kernel_launch(void* const* d_in, const int* in_sizes, int n_in,
                              void* d_out, int out_size, void* d_ws, size_t ws_size,
                              hipStream_t stream) {
    (void)in_sizes; (void)n_in; (void)out_size; (void)ws_size;
    const float* codewords = (const float*)d_in[1];  // d_in[0] = info (unused)
    const float* sigma     = (const float*)d_in[2];
    float* out = (float*)d_out;

    char* ws = (char*)d_ws;
    __bf16* mubf   = (__bf16*)ws;                                  // 4 MB
    float*  hq     = (float*)(ws + (size_t)NB * ND * 2);           // 16 KB
    float*  sumexp = hq + NB;                                      // 16 KB

    prep_kernel<<<NB / 4, 256, 0, stream>>>(codewords, mubf, hq, sumexp);
    gram_lse_kernel<<<NBLK, 256, 0, stream>>>(mubf, hq, sigma, sumexp);
    finalize_kernel<<<1, 1024, 0, stream>>>(sumexp, sigma, out);
}

// Round 5
// 111.802 us; speedup vs baseline: 1.3008x; 1.3008x over previous
//
#include <hip/hip_runtime.h>
#include <math.h>

// Problem constants (reference: BATCH=4096, DIM=512, sigma = s*I).
#define NB 4096
#define ND 512
#define TILE 128
#define BK 32                      // LDS sub-tile k-depth (layout identical to R1)
#define NEPOCH 8                   // 8 epochs x 2 sub-tiles x k32 = K=512

typedef __bf16 bf16x8 __attribute__((ext_vector_type(8)));
typedef float floatx4 __attribute__((ext_vector_type(4)));

__device__ inline void async_load16(const void* g, void* l) {
    __builtin_amdgcn_global_load_lds((const __attribute__((address_space(1))) void*)g,
                                     (__attribute__((address_space(3))) void*)l, 16, 0, 0);
}

// Kernel 1: cast mu -> bf16 (one wave per row) with NON-TEMPORAL stores so
// mubf lines are not left dirty+pinned in the writer XCD's L2 (gram's
// cross-XCD reads would pay dirty-forwarding); hq[i] = 0.5*sum(bf16(x)^2);
// zero sumexp (ws is re-poisoned to 0xAA before every timed launch).
__global__ __launch_bounds__(256) void prep_kernel(const float* __restrict__ mu,
                                                   __bf16* __restrict__ mubf,
                                                   float* __restrict__ hq,
                                                   float* __restrict__ sumexp) {
    const int t = threadIdx.x;
    const int wave = t >> 6, lane = t & 63;
    const int row = blockIdx.x * 4 + wave;
    const float4* src = (const float4*)(mu + (size_t)row * ND) + lane * 2;
    const float4 v0 = src[0], v1 = src[1];
    bf16x8 pack;
    pack[0] = (__bf16)v0.x; pack[1] = (__bf16)v0.y;
    pack[2] = (__bf16)v0.z; pack[3] = (__bf16)v0.w;
    pack[4] = (__bf16)v1.x; pack[5] = (__bf16)v1.y;
    pack[6] = (__bf16)v1.z; pack[7] = (__bf16)v1.w;
    __builtin_nontemporal_store(pack, (bf16x8*)(mubf + (size_t)row * ND) + lane);
    float sq = 0.0f;
    #pragma unroll
    for (int e = 0; e < 8; e++) { float f = (float)pack[e]; sq += f * f; }
    #pragma unroll
    for (int off = 32; off > 0; off >>= 1) sq += __shfl_down(sq, off, 64);
    if (lane == 0) {
        hq[row] = 0.5f * sq;
        sumexp[row] = 0.0f;
    }
}

// Kernel 2: R1 structure (m97-style coalesced global_load_lds staging,
// 128x128 tile, 4 waves x 64x64, full matrix — symmetry abandoned) with
// BK=64 per barrier-pair: two BK=32 sub-tiles staged per epoch, so only
// 8 vmcnt(0)+barrier drains instead of 16. LDS layout per sub-tile is
// IDENTICAL to R1 (k-stride 32), keeping staging coalescing and ds_read
// patterns proven at 47.8 us.
// expo[i,j] = (G_ij - hq_i - hq_j)/s <= ~0 (max on diag = 0), so plain
// sum-of-exp is safe without an online max.
__global__ __launch_bounds__(256) void gram_lse_kernel(const __bf16* __restrict__ mubf,
                                                       const float* __restrict__ hq,
                                                       const float* __restrict__ sigma,
                                                       float* __restrict__ sumexp) {
    __shared__ alignas(16) __bf16 As[2][TILE * BK];   // 2 sub-tiles x 8 KB
    __shared__ alignas(16) __bf16 Bs[2][TILE * BK];

    const int t = threadIdx.x;
    const int row0 = blockIdx.y * TILE;
    const int col0 = blockIdx.x * TILE;
    const int wave = t >> 6;
    const int lane = t & 63;
    const int r16 = lane & 15;
    const int quad = lane >> 4;
    const int rw = (wave >> 1) * 64;   // wave's row offset within tile
    const int cw = (wave & 1) * 64;    // wave's col offset within tile

    // Staging: thread t moves 16B per instr: row (t>>2), k elems [(t&3)*8,+8)
    const int srow = t >> 2;
    const int skoff = (t & 3) * 8;
    const __bf16* gA0 = mubf + (size_t)(row0 + srow) * ND + skoff;
    const __bf16* gA1 = gA0 + (size_t)64 * ND;
    const __bf16* gB0 = mubf + (size_t)(col0 + srow) * ND + skoff;
    const __bf16* gB1 = gB0 + (size_t)64 * ND;

    floatx4 acc[4][4];
    #pragma unroll
    for (int i = 0; i < 4; i++)
        #pragma unroll
        for (int j = 0; j < 4; j++) {
            floatx4 z = {0.f, 0.f, 0.f, 0.f};
            acc[i][j] = z;
        }

    for (int ep = 0; ep < NEPOCH; ep++) {
        const int k0 = ep * 64;            // this epoch covers k in [k0, k0+64)
        __syncthreads();                   // protect LDS from prior reads
        #pragma unroll
        for (int s = 0; s < 2; s++) {      // two BK=32 sub-tiles
            const int ks = k0 + s * BK;
            async_load16(gA0 + ks, &As[s][t * 8]);
            async_load16(gA1 + ks, &As[s][2048 + t * 8]);
            async_load16(gB0 + ks, &Bs[s][t * 8]);
            async_load16(gB1 + ks, &Bs[s][2048 + t * 8]);
        }
        __syncthreads();                   // single vmcnt(0) drain per epoch

        #pragma unroll
        for (int s = 0; s < 2; s++) {
            bf16x8 a[4], b[4];
            #pragma unroll
            for (int i = 0; i < 4; i++)
                a[i] = *(const bf16x8*)&As[s][(rw + i * 16 + r16) * BK + quad * 8];
            #pragma unroll
            for (int j = 0; j < 4; j++)
                b[j] = *(const bf16x8*)&Bs[s][(cw + j * 16 + r16) * BK + quad * 8];
            #pragma unroll
            for (int i = 0; i < 4; i++)
                #pragma unroll
                for (int j = 0; j < 4; j++)
                    acc[i][j] = __builtin_amdgcn_mfma_f32_16x16x32_bf16(a[i], b[j], acc[i][j], 0, 0, 0);
        }
    }

    // Epilogue. C/D layout (m89-verified): col = lane&15, row = quad*4 + reg.
    const float inv_s = 1.0f / sigma[0];
    float hqc[4];
    #pragma unroll
    for (int j = 0; j < 4; j++) hqc[j] = hq[col0 + cw + j * 16 + r16];

    #pragma unroll
    for (int i = 0; i < 4; i++) {
        #pragma unroll
        for (int r = 0; r < 4; r++) {
            const int row = row0 + rw + i * 16 + quad * 4 + r;
            const float hr = hq[row];
            float rs = 0.0f;
            #pragma unroll
            for (int j = 0; j < 4; j++)
                rs += __expf((acc[i][j][r] - hr - hqc[j]) * inv_s);
            rs += __shfl_xor(rs, 1, 64);
            rs += __shfl_xor(rs, 2, 64);
            rs += __shfl_xor(rs, 4, 64);
            rs += __shfl_xor(rs, 8, 64);
            if (r16 == 0) atomicAdd(&sumexp[row], rs);
        }
    }
}

// Kernel 3: entropy = D/2 + ln(B) + (D/2)ln(2*pi*s) - mean_i log(sumexp_i)
__global__ __launch_bounds__(1024) void finalize_kernel(const float* __restrict__ sumexp,
                                                        const float* __restrict__ sigma,
                                                        float* __restrict__ out) {
    const int t = threadIdx.x;
    float local = 0.0f;
    for (int i = t; i < NB; i += 1024) local += logf(sumexp[i]);
    #pragma unroll
    for (int off = 32; off > 0; off >>= 1) local += __shfl_down(local, off, 64);
    __shared__ float red[16];
    if ((t & 63) == 0) red[t >> 6] = local;
    __syncthreads();
    if (t == 0) {
        double tot = 0.0;
        #pragma unroll
        for (int i = 0; i < 16; i++) tot += (double)red[i];
        const double s = (double)sigma[0];
        const double ent = (double)(ND / 2)
                         + log((double)NB)
                         + (double)(ND / 2) * log(2.0 * M_PI * s)
                         - tot / (double)NB;
        out[0] = (float)ent;
        out[1] = (float)ent;
    }
}

extern "C" void kernel_launch(void* const* d_in, const int* in_sizes, int n_in,
                              void* d_out, int out_size, void* d_ws, size_t ws_size,
                              hipStream_t stream) {
    (void)in_sizes; (void)n_in; (void)out_size; (void)ws_size;
    const float* codewords = (const float*)d_in[1];  // d_in[0] = info (unused)
    const float* sigma     = (const float*)d_in[2];
    float* out = (float*)d_out;

    char* ws = (char*)d_ws;
    __bf16* mubf   = (__bf16*)ws;                                  // 4 MB
    float*  hq     = (float*)(ws + (size_t)NB * ND * 2);           // 16 KB
    float*  sumexp = hq + NB;                                      // 16 KB

    prep_kernel<<<NB / 4, 256, 0, stream>>>(codewords, mubf, hq, sumexp);
    dim3 grid(NB / TILE, NB / TILE);   // 32 x 32 tiles, 1024 blocks (~4/CU)
    gram_lse_kernel<<<grid, 256, 0, stream>>>(mubf, hq, sigma, sumexp);
    finalize_kernel<<<1, 1024, 0, stream>>>(sumexp, sigma, out);
}